// Round 1
// baseline (167.508 us; speedup 1.0000x reference)
//
#include <hip/hip_runtime.h>
#include <stdint.h>

#define NN 4096
#define MM 8192
#define DD 512

typedef __bf16 bf16x8 __attribute__((ext_vector_type(8)));
typedef float f32x4 __attribute__((ext_vector_type(4)));

__device__ __forceinline__ void load_lds16(const void* g, void* l) {
  // async global -> LDS, 16B per lane; LDS dest is wave-uniform base + lane*16,
  // our chunk layout is lane-contiguous by construction.
  __builtin_amdgcn_global_load_lds(
      (const __attribute__((address_space(1))) unsigned int*)g,
      (__attribute__((address_space(3))) unsigned int*)l, 16, 0, 0);
}

__global__ __launch_bounds__(256) void init_out_kernel(float* __restrict__ out,
                                                       const float* __restrict__ IC) {
  int i = blockIdx.x * 256 + threadIdx.x;
  if (i < NN) out[i] = IC[0];
}

// One wave per row: fp32 -> bf16 convert + exact fp32 row-norm.
__global__ __launch_bounds__(256) void convert_norm_kernel(
    const float* __restrict__ X, const float* __restrict__ SV,
    bf16x8* __restrict__ Xb, bf16x8* __restrict__ SVb,
    float* __restrict__ x2, float* __restrict__ sv2) {
  int wid = (blockIdx.x * 256 + threadIdx.x) >> 6;  // global wave id = row id
  int lane = threadIdx.x & 63;
  const float* src;
  bf16x8* dst;
  float* nrm;
  if (wid < NN) {
    src = X + (size_t)wid * DD;
    dst = Xb + (size_t)wid * (DD / 8);
    nrm = x2 + wid;
  } else {
    int r = wid - NN;
    src = SV + (size_t)r * DD;
    dst = SVb + (size_t)r * (DD / 8);
    nrm = sv2 + r;
  }
  const f32x4* s4 = ((const f32x4*)src) + lane * 2;  // 8 floats per lane = full 512/row
  f32x4 a = s4[0];
  f32x4 b = s4[1];
  float sum = a.x * a.x + a.y * a.y + a.z * a.z + a.w * a.w +
              b.x * b.x + b.y * b.y + b.z * b.z + b.w * b.w;
  bf16x8 o;
  o[0] = (__bf16)a.x; o[1] = (__bf16)a.y; o[2] = (__bf16)a.z; o[3] = (__bf16)a.w;
  o[4] = (__bf16)b.x; o[5] = (__bf16)b.y; o[6] = (__bf16)b.z; o[7] = (__bf16)b.w;
  dst[lane] = o;
#pragma unroll
  for (int m = 32; m >= 1; m >>= 1) sum += __shfl_xor(sum, m, 64);
  if (lane == 0) *nrm = sum;
}

// 128x128 tile (BM over N, BN over M), BK=64, 4 waves in 2x2, each wave 64x64
// via 4x4 grid of 16x16x32 bf16 MFMA. LDS layout: 16B chunks, k-major
// [kg (0..7)][row (0..127)] -> staging chunk index == lds index (lane-contig),
// fragment ds_read_b128 gets only free 2-way bank conflicts.
__global__ __launch_bounds__(256) void rbf_gemm_kernel(
    const bf16x8* __restrict__ Xb, const bf16x8* __restrict__ SVb,
    const float* __restrict__ x2, const float* __restrict__ sv2,
    const float* __restrict__ DC, const float* __restrict__ gamma_p,
    float* __restrict__ out) {
  __shared__ bf16x8 As[8 * 128];  // 16 KB
  __shared__ bf16x8 Bs[8 * 128];  // 16 KB

  const int t = threadIdx.x;
  const int lane = t & 63;
  const int wave = t >> 6;
  const int wave_m = wave & 1;   // m-dir (cols of C)
  const int wave_n = wave >> 1;  // n-dir (rows of C)
  const int col = lane & 15;
  const int quad = lane >> 4;

  const int n0 = blockIdx.x * 128;
  const int m0 = blockIdx.y * 128;

  f32x4 acc[4][4];
  const f32x4 fzero = {0.f, 0.f, 0.f, 0.f};
#pragma unroll
  for (int i = 0; i < 4; ++i)
#pragma unroll
    for (int j = 0; j < 4; ++j) acc[i][j] = fzero;

  for (int kt = 0; kt < 8; ++kt) {  // K tiles of 64
#pragma unroll
    for (int it = 0; it < 4; ++it) {
      int c = it * 256 + t;   // chunk id == lds index (k-major layout)
      int r = c & 127;        // tile row
      int kg = c >> 7;        // 8-elem k-group within BK
      const bf16x8* ga = Xb + (size_t)(n0 + r) * (DD / 8) + kt * 8 + kg;
      const bf16x8* gb = SVb + (size_t)(m0 + r) * (DD / 8) + kt * 8 + kg;
      load_lds16(ga, &As[c]);
      load_lds16(gb, &Bs[c]);
    }
    __syncthreads();  // drains vmcnt before barrier (compiler-emitted)
#pragma unroll
    for (int ks = 0; ks < 2; ++ks) {
      bf16x8 af[4], bfr[4];
      const int kbase = (ks * 4 + quad) * 128;
#pragma unroll
      for (int i = 0; i < 4; ++i) af[i] = As[kbase + wave_n * 64 + i * 16 + col];
#pragma unroll
      for (int j = 0; j < 4; ++j) bfr[j] = Bs[kbase + wave_m * 64 + j * 16 + col];
#pragma unroll
      for (int i = 0; i < 4; ++i)
#pragma unroll
        for (int j = 0; j < 4; ++j)
          acc[i][j] = __builtin_amdgcn_mfma_f32_16x16x32_bf16(af[i], bfr[j], acc[i][j], 0, 0, 0);
    }
    __syncthreads();
  }

  // Epilogue: k = exp(-g*max(x2+sv2-2c,0)) * DC, reduce over m, atomicAdd.
  const float g = gamma_p[0];
  const float c2 = g * 1.4426950408889634f;  // gamma * log2(e)

  float sv2v[4], dcv[4];
#pragma unroll
  for (int j = 0; j < 4; ++j) {
    int m = m0 + wave_m * 64 + j * 16 + col;
    sv2v[j] = sv2[m];
    dcv[j] = DC[m];
  }

#pragma unroll
  for (int i = 0; i < 4; ++i) {
    const int nb = n0 + wave_n * 64 + i * 16 + quad * 4;  // rows nb..nb+3
    f32x4 xv = *(const f32x4*)(x2 + nb);
    float part[4] = {0.f, 0.f, 0.f, 0.f};
#pragma unroll
    for (int j = 0; j < 4; ++j) {
#pragma unroll
      for (int r = 0; r < 4; ++r) {
        float d2 = xv[r] + sv2v[j] - 2.0f * acc[i][j][r];
        d2 = fmaxf(d2, 0.0f);
        part[r] += exp2f(-c2 * d2) * dcv[j];
      }
    }
    // reduce across the 16 col-lanes (lane bits 0..3) within each quad
#pragma unroll
    for (int m = 1; m < 16; m <<= 1) {
#pragma unroll
      for (int r = 0; r < 4; ++r) part[r] += __shfl_xor(part[r], m, 64);
    }
    if (col == 0) {
#pragma unroll
      for (int r = 0; r < 4; ++r) atomicAdd(&out[nb + r], part[r]);
    }
  }
}

extern "C" void kernel_launch(void* const* d_in, const int* in_sizes, int n_in,
                              void* d_out, int out_size, void* d_ws, size_t ws_size,
                              hipStream_t stream) {
  const float* X = (const float*)d_in[0];
  const float* SV = (const float*)d_in[1];
  const float* DC = (const float*)d_in[2];
  const float* IC = (const float*)d_in[3];
  const float* gamma = (const float*)d_in[4];
  float* out = (float*)d_out;

  char* ws = (char*)d_ws;
  bf16x8* Xb = (bf16x8*)ws;                                   // 4 MB
  bf16x8* SVb = (bf16x8*)(ws + (size_t)NN * DD * 2);          // 8 MB
  float* x2 = (float*)(ws + (size_t)(NN + MM) * DD * 2);      // 16 KB
  float* sv2 = x2 + NN;                                       // 32 KB

  init_out_kernel<<<(NN + 255) / 256, 256, 0, stream>>>(out, IC);
  convert_norm_kernel<<<(NN + MM) / 4, 256, 0, stream>>>(X, SV, Xb, SVb, x2, sv2);
  dim3 grid(NN / 128, MM / 128);
  rbf_gemm_kernel<<<grid, 256, 0, stream>>>(Xb, SVb, x2, sv2, DC, gamma, out);
}